// Round 4
// baseline (484.854 us; speedup 1.0000x reference)
//
#include <hip/hip_runtime.h>
#include <hip/hip_bf16.h>
#include <math.h>

#define DMODEL 256
#define NH 8
#define DKH 32
#define SEQ 197
#define BATCH 64
#define NPAT 196
#define FFDIM 1024
#define KCONV 768
#define EPSLN 1e-5f
#define MROWS (BATCH * SEQ)  // 12608
#define SP 224               // SEQ padded to 7 super-tiles of 32

typedef __attribute__((ext_vector_type(8))) short short8;
typedef __attribute__((ext_vector_type(4))) short short4v;
typedef __attribute__((ext_vector_type(4))) float floatx4;

__device__ inline short f2b(float f) {
  unsigned u = __float_as_uint(f);
  unsigned r = (u + 0x7FFFu + ((u >> 16) & 1u)) >> 16;
  return (short)r;
}
__device__ inline float b2f(short s) {
  return __uint_as_float(((unsigned)(unsigned short)s) << 16);
}

// async global->LDS 16B DMA (lds dest must be wave-uniform-base + lane*16)
typedef const __attribute__((address_space(1))) unsigned int gu32;
typedef __attribute__((address_space(3))) unsigned int lu32;
__device__ __forceinline__ void gl_lds16(const void* g, void* l) {
  __builtin_amdgcn_global_load_lds((gu32*)g, (lu32*)l, 16, 0, 0);
}
// chunk swizzle: spreads ds_read_b128 banks to 2-way (free)
__device__ __forceinline__ int swz(int row) { return (row ^ (row >> 2)) & 3; }

// ---------------------------------------------------------------------------
// fp32 -> bf16 bulk convert of enc image + dec_in (8 elems/thread)
// ---------------------------------------------------------------------------
__global__ __launch_bounds__(256) void convert_inputs(
    const float* __restrict__ img, const float* __restrict__ dec,
    short* __restrict__ img_bf, short* __restrict__ dec_bf)
{
  const int NI = (BATCH * 3 * 224 * 224) / 8;  // 1204224
  const int ND = (MROWS * DMODEL) / 8;         // 403456
  int i = blockIdx.x * 256 + threadIdx.x;
  if (i >= NI + ND) return;
  const float* src; short* dst; int j;
  if (i < NI) { src = img; dst = img_bf; j = i; }
  else        { src = dec; dst = dec_bf; j = i - NI; }
  float4 a0 = ((const float4*)src)[j * 2];
  float4 a1 = ((const float4*)src)[j * 2 + 1];
  short8 o;
  o[0] = f2b(a0.x); o[1] = f2b(a0.y); o[2] = f2b(a0.z); o[3] = f2b(a0.w);
  o[4] = f2b(a1.x); o[5] = f2b(a1.y); o[6] = f2b(a1.z); o[7] = f2b(a1.w);
  ((short8*)dst)[j] = o;
}

// ---------------------------------------------------------------------------
// One-shot weight prep: fp32 -> bf16, with QKV / QK concatenation.
// ---------------------------------------------------------------------------
__global__ __launch_bounds__(256) void prep_weights(
    const float* wq1, const float* wk1, const float* wv1,
    const float* bq1, const float* bk1, const float* bv1,
    const float* wq2, const float* wk2, const float* bq2, const float* bk2,
    const float* wv2s, const float* wo1, const float* wo2,
    const float* ffw1, const float* ffw2, const float* convw,
    short* Wqkv1, float* Bqkv1, short* Wqk2, float* Bqk2,
    short* Wv2, short* Wo1, short* Wo2, short* Wff1, short* Wff2, short* Wconv)
{
  int i = blockIdx.x * 256 + threadIdx.x;
  if (i < 65536) {
    Wqkv1[i] = f2b(wq1[i]); Wqkv1[65536 + i] = f2b(wk1[i]); Wqkv1[131072 + i] = f2b(wv1[i]);
    Wqk2[i] = f2b(wq2[i]);  Wqk2[65536 + i] = f2b(wk2[i]);
    Wv2[i] = f2b(wv2s[i]);  Wo1[i] = f2b(wo1[i]);  Wo2[i] = f2b(wo2[i]);
  }
  if (i < 262144) { Wff1[i] = f2b(ffw1[i]); Wff2[i] = f2b(ffw2[i]); }
  if (i < 196608) { Wconv[i] = f2b(convw[i]); }
  if (i < 256) {
    Bqkv1[i] = bq1[i]; Bqkv1[256 + i] = bk1[i]; Bqkv1[512 + i] = bv1[i];
    Bqk2[i] = bq2[i];  Bqk2[256 + i] = bk2[i];
  }
}

// Pack mask (S,S) int32 -> per-row 4x uint64 bitmask; plus all-ones table.
__global__ void mask_pack(const int* __restrict__ mask,
                          unsigned long long* __restrict__ bits,
                          unsigned long long* __restrict__ ones)
{
  int idx = blockIdx.x * 256 + threadIdx.x;
  if (idx >= SEQ * 4) return;
  int r = idx >> 2, w = idx & 3;
  unsigned long long bb = 0ull, oo = 0ull;
  for (int j = 0; j < 64; j++) {
    int c = w * 64 + j;
    if (c < SEQ) {
      oo |= (1ull << j);
      if (mask[r * SEQ + c] != 0) bb |= (1ull << j);
    }
  }
  bits[idx] = bb;
  ones[idx] = oo;
}

// cls row (196, appended at END) + pos -> bf16 e
__global__ void cls_kernel(const float* __restrict__ cls, const float* __restrict__ pos,
                           short* __restrict__ e)
{
  int b = blockIdx.x, d = threadIdx.x;
  e[((size_t)b * SEQ + NPAT) * DMODEL + d] = f2b(cls[d] + pos[NPAT * DMODEL + d]);
}

// ---------------------------------------------------------------------------
// 128x128-tile bf16 MFMA GEMM (m97 structure): C = A @ W^T (+bias)(+res)(+relu)
// A bf16 (M,K) row-major; W bf16 (N,K) row-major; BK=32.
// Staging: global_load_lds dwordx4, XOR-swizzled 16B chunks.
// 4 waves, each 64x64 via 4x4 mfma_f32_16x16x32_bf16.
// ---------------------------------------------------------------------------
__global__ __launch_bounds__(256) void gemm128(
    const short* __restrict__ A, const short* __restrict__ W,
    const float* __restrict__ bias, const float* __restrict__ res,
    float* __restrict__ outf, short* __restrict__ outb,
    int M, int N, int K, int relu)
{
  __shared__ short Al[128 * 32];
  __shared__ short Bl[128 * 32];
  int m0 = blockIdx.x * 128, n0 = blockIdx.y * 128;
  int t = threadIdx.x;
  int wave = t >> 6, lane = t & 63;
  int wm = (wave & 1) * 64, wn = (wave >> 1) * 64;
  int ml = lane & 15, quad = lane >> 4;

  // staging addresses: thread t pass p handles LDS row (t>>2)+p*64, chunk t&3
  int rA0 = t >> 2, rA1 = rA0 + 64;
  int c0 = (t & 3) ^ swz(rA0);
  int c1 = (t & 3) ^ swz(rA1);
  const short* gA0 = A + (size_t)min(m0 + rA0, M - 1) * K + c0 * 8;
  const short* gA1 = A + (size_t)min(m0 + rA1, M - 1) * K + c1 * 8;
  const short* gB0 = W + (size_t)(n0 + rA0) * K + c0 * 8;
  const short* gB1 = W + (size_t)(n0 + rA1) * K + c1 * 8;
  short* lA0 = &Al[t * 8];
  short* lA1 = &Al[t * 8 + 2048];
  short* lB0 = &Bl[t * 8];
  short* lB1 = &Bl[t * 8 + 2048];

  // fragment read offsets (shorts), loop-invariant
  int offA[4], offB[4];
#pragma unroll
  for (int i = 0; i < 4; i++) {
    int ra = wm + i * 16 + ml;
    offA[i] = ra * 32 + ((quad ^ swz(ra)) * 8);
    int rb = wn + i * 16 + ml;
    offB[i] = rb * 32 + ((quad ^ swz(rb)) * 8);
  }

  floatx4 z = {0.f, 0.f, 0.f, 0.f};
  floatx4 acc[4][4] = {{z, z, z, z}, {z, z, z, z}, {z, z, z, z}, {z, z, z, z}};

  for (int k0 = 0; k0 < K; k0 += 32) {
    __syncthreads();
    gl_lds16(gA0 + k0, lA0);
    gl_lds16(gA1 + k0, lA1);
    gl_lds16(gB0 + k0, lB0);
    gl_lds16(gB1 + k0, lB1);
    __builtin_amdgcn_s_waitcnt(0x0F70);  // vmcnt(0)
    __syncthreads();
    short8 af[4], bf[4];
#pragma unroll
    for (int i = 0; i < 4; i++) {
      af[i] = *(const short8*)&Al[offA[i]];
      bf[i] = *(const short8*)&Bl[offB[i]];
    }
#pragma unroll
    for (int i = 0; i < 4; i++)
#pragma unroll
      for (int j = 0; j < 4; j++)
        acc[i][j] = __builtin_amdgcn_mfma_f32_16x16x32_bf16(af[i], bf[j], acc[i][j], 0, 0, 0);
  }
#pragma unroll
  for (int i = 0; i < 4; i++)
#pragma unroll
    for (int j = 0; j < 4; j++)
#pragma unroll
      for (int rr = 0; rr < 4; rr++) {
        int row = m0 + wm + i * 16 + quad * 4 + rr;
        if (row >= M) continue;
        int col = n0 + wn + j * 16 + ml;
        float v = acc[i][j][rr] + bias[col];
        if (res) v += res[(size_t)row * N + col];
        if (relu) v = fmaxf(v, 0.f);
        if (outf) outf[(size_t)row * N + col] = v;
        if (outb) outb[(size_t)row * N + col] = f2b(v);
      }
}

// ---------------------------------------------------------------------------
// Patch-embed conv as 128x128 MFMA GEMM, im2col A from bf16 image.
// M=12544 (=98*128 exact), K=768, N=256. Epilogue: +cb+pos -> bf16 e.
// ---------------------------------------------------------------------------
__global__ __launch_bounds__(256) void conv128(
    const short* __restrict__ img, const short* __restrict__ W,
    const float* __restrict__ cb, const float* __restrict__ pos,
    short* __restrict__ e)
{
  __shared__ short Al[128 * 32];
  __shared__ short Bl[128 * 32];
  int m0 = blockIdx.x * 128, n0 = blockIdx.y * 128;
  int t = threadIdx.x;
  int wave = t >> 6, lane = t & 63;
  int wm = (wave & 1) * 64, wn = (wave >> 1) * 64;
  int ml = lane & 15, quad = lane >> 4;

  // A staging: per-thread invariants for both passes
  const short* gA[2];
  int halfrow[2];
  short* lA[2];
#pragma unroll
  for (int p = 0; p < 2; p++) {
    int rowc = (t >> 2) + p * 64;
    int m = m0 + rowc;
    int b = m / NPAT, pp = m - b * NPAT;
    int py = pp / 14, px = pp - py * 14;
    int chunk = (t & 3) ^ swz(rowc);
    gA[p] = img + (size_t)b * 3 * 50176 + (size_t)(py * 16) * 224 + px * 16 + (chunk & 1) * 8;
    halfrow[p] = chunk >> 1;
    lA[p] = &Al[t * 8 + p * 2048];
  }
  int rB0 = t >> 2, rB1 = rB0 + 64;
  const short* gB0 = W + (size_t)(n0 + rB0) * KCONV + ((t & 3) ^ swz(rB0)) * 8;
  const short* gB1 = W + (size_t)(n0 + rB1) * KCONV + ((t & 3) ^ swz(rB1)) * 8;
  short* lB0 = &Bl[t * 8];
  short* lB1 = &Bl[t * 8 + 2048];

  int offA[4], offB[4];
#pragma unroll
  for (int i = 0; i < 4; i++) {
    int ra = wm + i * 16 + ml;
    offA[i] = ra * 32 + ((quad ^ swz(ra)) * 8);
    int rb = wn + i * 16 + ml;
    offB[i] = rb * 32 + ((quad ^ swz(rb)) * 8);
  }

  floatx4 z = {0.f, 0.f, 0.f, 0.f};
  floatx4 acc[4][4] = {{z, z, z, z}, {z, z, z, z}, {z, z, z, z}, {z, z, z, z}};

  for (int k0 = 0; k0 < KCONV; k0 += 32) {
    int ch = k0 >> 8;
    int rr0 = (k0 & 255) >> 4;
    __syncthreads();
#pragma unroll
    for (int p = 0; p < 2; p++)
      gl_lds16(gA[p] + (size_t)ch * 50176 + (rr0 + halfrow[p]) * 224, lA[p]);
    gl_lds16(gB0 + k0, lB0);
    gl_lds16(gB1 + k0, lB1);
    __builtin_amdgcn_s_waitcnt(0x0F70);
    __syncthreads();
    short8 af[4], bf[4];
#pragma unroll
    for (int i = 0; i < 4; i++) {
      af[i] = *(const short8*)&Al[offA[i]];
      bf[i] = *(const short8*)&Bl[offB[i]];
    }
#pragma unroll
    for (int i = 0; i < 4; i++)
#pragma unroll
      for (int j = 0; j < 4; j++)
        acc[i][j] = __builtin_amdgcn_mfma_f32_16x16x32_bf16(af[i], bf[j], acc[i][j], 0, 0, 0);
  }
#pragma unroll
  for (int i = 0; i < 4; i++)
#pragma unroll
    for (int j = 0; j < 4; j++)
#pragma unroll
      for (int rr = 0; rr < 4; rr++) {
        int mrow = m0 + wm + i * 16 + quad * 4 + rr;
        int b2 = mrow / NPAT, p2 = mrow - b2 * NPAT;
        int col = n0 + wn + j * 16 + ml;
        e[((size_t)b2 * SEQ + p2) * DMODEL + col] =
            f2b(acc[i][j][rr] + cb[col] + pos[p2 * DMODEL + col]);
      }
}

// ---------------------------------------------------------------------------
// MFMA flash attention, S^T formulation. Grid (B*NH, 2); 4 waves/block;
// each wave processes 2 sequential 16-query tiles (K/V staged once).
// ---------------------------------------------------------------------------
__global__ __launch_bounds__(256) void attn_mfma(
    const short* __restrict__ qp, int qstr,
    const short* __restrict__ kp, int kstr,
    const short* __restrict__ vp, int vstr,
    const unsigned long long* __restrict__ mbits,
    short* __restrict__ op)
{
  __shared__ short ks[SP][40];
  __shared__ short vt[DKH][SP + 8];
  __shared__ short ps[4][16][40];
  int bh = blockIdx.x;
  int b = bh >> 3, h = bh & 7;
  int t = threadIdx.x;
  int wave = t >> 6, lane = t & 63;
  int ml = lane & 15, quad = lane >> 4;

  const short* kb = kp + (size_t)b * SEQ * kstr + h * DKH;
  const short* vb = vp + (size_t)b * SEQ * vstr + h * DKH;
  for (int idx = t; idx < SEQ * 4; idx += 256) {
    int s = idx >> 2, c = (idx & 3) * 8;
    *(short8*)&ks[s][c] = *(const short8*)(kb + (size_t)s * kstr + c);
  }
  for (int idx = t; idx < SEQ * 4; idx += 256) {
    int s = idx >> 2, c = (idx & 3) * 8;
    short8 v8 = *(const short8*)(vb + (size_t)s * vstr + c);
#pragma unroll
    for (int j = 0; j < 8; j++) vt[c + j][s] = v8[j];
  }
  for (int idx = t; idx < DKH * (SP - SEQ); idx += 256) {
    int d = idx / (SP - SEQ), j = SEQ + idx - d * (SP - SEQ);
    vt[d][j] = 0;
  }
  __syncthreads();

  const float scale = 0.17677669529663687f;  // 1/sqrt(32)
  floatx4 z = {0.f, 0.f, 0.f, 0.f};

  for (int tt = 0; tt < 2; tt++) {
    int ti = blockIdx.y * 8 + wave * 2 + tt;  // 16-query tile index, 0..12 valid
    int q0 = ti * 16;
    if (q0 >= SEQ) continue;
    int qrow = q0 + ml;
    int qc = qrow < SEQ ? qrow : SEQ - 1;
    short8 qf = *(const short8*)(qp + ((size_t)b * SEQ + qc) * qstr + h * DKH + quad * 8);
    const unsigned long long* mrow = mbits + (size_t)qc * 4;

    floatx4 accO0 = z, accO1 = z;
    float mrun = -1e30f, lrun = 0.f;

    for (int st = 0; st < 7; st++) {
      int j0 = st * 32;
      short8 k0 = *(const short8*)&ks[j0 + ml][quad * 8];
      short8 k1 = *(const short8*)&ks[j0 + 16 + ml][quad * 8];
      floatx4 s0 = __builtin_amdgcn_mfma_f32_16x16x32_bf16(k0, qf, z, 0, 0, 0);
      floatx4 s1 = __builtin_amdgcn_mfma_f32_16x16x32_bf16(k1, qf, z, 0, 0, 0);
      unsigned long long mb = mrow[j0 >> 6] >> (j0 & 63);
      float sv[8];
#pragma unroll
      for (int r = 0; r < 4; r++) {
        int jl = quad * 4 + r;
        sv[r]     = ((mb >> jl) & 1ull)        ? s0[r] * scale : -1e38f;
        sv[4 + r] = ((mb >> (16 + jl)) & 1ull) ? s1[r] * scale : -1e38f;
      }
      float tm = sv[0];
#pragma unroll
      for (int i = 1; i < 8; i++) tm = fmaxf(tm, sv[i]);
      tm = fmaxf(tm, __shfl_xor(tm, 16));
      tm = fmaxf(tm, __shfl_xor(tm, 32));
      float nm = fmaxf(mrun, tm);
      float alpha = __expf(mrun - nm);
      float pv[8];
      float psum = 0.f;
#pragma unroll
      for (int i = 0; i < 8; i++) { pv[i] = __expf(sv[i] - nm); psum += pv[i]; }
      psum += __shfl_xor(psum, 16);
      psum += __shfl_xor(psum, 32);
      lrun = lrun * alpha + psum;
      mrun = nm;
      accO0 = accO0 * alpha;
      accO1 = accO1 * alpha;
      short4v p0, p1;
#pragma unroll
      for (int r = 0; r < 4; r++) { p0[r] = f2b(pv[r]); p1[r] = f2b(pv[4 + r]); }
      *(short4v*)&ps[wave][ml][quad * 4]      = p0;
      *(short4v*)&ps[wave][ml][16 + quad * 4] = p1;
      __asm__ volatile("s_waitcnt lgkmcnt(0)" ::: "memory");  // wave-local RAW
      short8 pf = *(const short8*)&ps[wave][ml][quad * 8];
      short8 vf0 = *(const short8*)&vt[ml][j0 + quad * 8];
      short8 vf1 = *(const short8*)&vt[16 + ml][j0 + quad * 8];
      accO0 = __builtin_amdgcn_mfma_f32_16x16x32_bf16(vf0, pf, accO0, 0, 0, 0);
      accO1 = __builtin_amdgcn_mfma_f32_16x16x32_bf16(vf1, pf, accO1, 0, 0, 0);
    }
    if (qrow < SEQ) {
      float inv = 1.f / lrun;
      short* ob = op + ((size_t)b * SEQ + qrow) * DMODEL + h * DKH;
      short4v o0, o1;
#pragma unroll
      for (int r = 0; r < 4; r++) {
        o0[r] = f2b(accO0[r] * inv);
        o1[r] = f2b(accO1[r] * inv);
      }
      *(short4v*)(ob + quad * 4)      = o0;
      *(short4v*)(ob + 16 + quad * 4) = o1;
    }
  }
}

// ---------------------------------------------------------------------------
// LayerNorm over D=256, one wave per row; optional bf16 copy.
// ---------------------------------------------------------------------------
__global__ __launch_bounds__(256) void ln_kernel(
    const float* __restrict__ x, const float* __restrict__ g,
    const float* __restrict__ bt, float* __restrict__ outf,
    short* __restrict__ outb)
{
  int wave = threadIdx.x >> 6, lane = threadIdx.x & 63;
  int row = blockIdx.x * 4 + wave;
  const float* xr = x + (size_t)row * DMODEL;
  float v0 = xr[lane], v1 = xr[lane + 64], v2 = xr[lane + 128], v3 = xr[lane + 192];
  float s = v0 + v1 + v2 + v3;
  for (int off = 32; off; off >>= 1) s += __shfl_down(s, off);
  s = __shfl(s, 0);
  float mean = s * (1.0f / DMODEL);
  float d0 = v0 - mean, d1 = v1 - mean, d2 = v2 - mean, d3 = v3 - mean;
  float vv = d0 * d0 + d1 * d1 + d2 * d2 + d3 * d3;
  for (int off = 32; off; off >>= 1) vv += __shfl_down(vv, off);
  vv = __shfl(vv, 0);
  float inv = rsqrtf(vv * (1.0f / DMODEL) + EPSLN);
  float r0 = d0 * inv * g[lane]       + bt[lane];
  float r1 = d1 * inv * g[lane + 64]  + bt[lane + 64];
  float r2 = d2 * inv * g[lane + 128] + bt[lane + 128];
  float r3 = d3 * inv * g[lane + 192] + bt[lane + 192];
  if (outf) {
    float* orow = outf + (size_t)row * DMODEL;
    orow[lane] = r0; orow[lane + 64] = r1; orow[lane + 128] = r2; orow[lane + 192] = r3;
  }
  if (outb) {
    short* orow = outb + (size_t)row * DMODEL;
    orow[lane] = f2b(r0); orow[lane + 64] = f2b(r1);
    orow[lane + 128] = f2b(r2); orow[lane + 192] = f2b(r3);
  }
}

// ---------------------------------------------------------------------------
extern "C" void kernel_launch(void* const* d_in, const int* in_sizes, int n_in,
                              void* d_out, int out_size, void* d_ws, size_t ws_size,
                              hipStream_t stream)
{
  const float* enc    = (const float*)d_in[0];
  const float* dec_in = (const float*)d_in[1];
  const int*   mask   = (const int*)  d_in[2];
  const float* conv_w = (const float*)d_in[3];
  const float* conv_b = (const float*)d_in[4];
  const float* cls    = (const float*)d_in[5];
  const float* pos    = (const float*)d_in[6];
  const float* ff_w1  = (const float*)d_in[7];
  const float* ff_b1  = (const float*)d_in[8];
  const float* ff_w2  = (const float*)d_in[9];
  const float* ff_b2  = (const float*)d_in[10];
  const float* ln1_g  = (const float*)d_in[11];
  const float* ln1_b  = (const float*)d_in[12];
  const float* ln2_g  = (const float*)d_in[13];
  const float* ln2_b  = (const float*)d_in[14];
  const float* ln3_g  = (const float*)d_in[15];
  const float* ln3_b  = (const float*)d_in[16];
  const float* a1_wq = (const float*)d_in[17]; const float* a1_bq = (const float*)d_in[18];
  const float* a1_wk = (const float*)d_in[19]; const float* a1_bk = (const float*)d_in[20];
  const float* a1_wv = (const float*)d_in[21]; const float* a1_bv = (const float*)d_in[22];
  const float* a1_wo = (const float*)d_in[23]; const float* a1_bo = (const float*)d_in[24];
  const float* a2_wq = (const float*)d_in[25]; const float* a2_bq = (const float*)d_in[26];
  const float* a2_wk = (const float*)d_in[27]; const float* a2_bk = (const float*)d_in[28];
  const float* a2_wv = (const float*)d_in[29]; const float* a2_bv = (const float*)d_in[30];
  const float* a2_wo = (const float*)d_in[31]; const float* a2_bo = (const float*)d_in[32];

  // ---- workspace layout ----
  char* wsB = (char*)d_ws;
  short* Wqkv1 = (short*)wsB;            // 196608 shorts
  short* Wqk2  = Wqkv1 + 196608;         // 131072
  short* Wv2   = Wqk2 + 131072;          // 65536
  short* Wo1   = Wv2 + 65536;            // 65536
  short* Wo2   = Wo1 + 65536;            // 65536
  short* Wff1  = Wo2 + 65536;            // 262144
  short* Wff2  = Wff1 + 262144;          // 262144
  short* Wconv = Wff2 + 262144;          // 196608
  float* Bqkv1 = (float*)(Wconv + 196608);
  float* Bqk2  = Bqkv1 + 768;
  unsigned long long* mbits = (unsigned long long*)(Bqk2 + 512);  // 788 u64
  unsigned long long* mones = mbits + 788;                        // 788 u64

  const size_t MB = 1048576;
  short* img_bf = (short*)(wsB + 3 * MB);    // 19,267,584 B
  short* dec_bf = (short*)(wsB + 23 * MB);   //  6,455,296 B
  short* e_bf   = (short*)(wsB + 30 * MB);   //  6,455,296 B
  short* qkv1   = (short*)(wsB + 37 * MB);   // 19,365,888 B
  short* o1     = (short*)(wsB + 57 * MB);   //  6,455,296 B
  short* qk2    = (short*)(wsB + 64 * MB);   // 12,910,592 B
  short* v2     = (short*)(wsB + 77 * MB);   //  6,455,296 B
  short* h_buf  = (short*)(wsB + 84 * MB);   // 25,821,184 B
  float* t_buf  = (float*)(wsB + 111 * MB);  // 12,910,592 B
  float* x1     = (float*)(wsB + 124 * MB);
  float* x2     = (float*)(wsB + 138 * MB);
  short* x2b    = (short*)(wsB + 152 * MB);
  short* o2     = o1;

  dim3 blk(256);
  const int M = MROWS;

  convert_inputs<<<6280, blk, 0, stream>>>(enc, dec_in, img_bf, dec_bf);
  prep_weights<<<1024, blk, 0, stream>>>(
      a1_wq, a1_wk, a1_wv, a1_bq, a1_bk, a1_bv,
      a2_wq, a2_wk, a2_bq, a2_bk, a2_wv, a1_wo, a2_wo,
      ff_w1, ff_w2, conv_w,
      Wqkv1, Bqkv1, Wqk2, Bqk2, Wv2, Wo1, Wo2, Wff1, Wff2, Wconv);
  mask_pack<<<4, blk, 0, stream>>>(mask, mbits, mones);

  // patch embed -> bf16 e
  conv128<<<dim3(98, 2), blk, 0, stream>>>(img_bf, Wconv, conv_b, pos, e_bf);
  cls_kernel<<<BATCH, DMODEL, 0, stream>>>(cls, pos, e_bf);

  // ---- attention 1: q=k=v=dec_in, no mask ----
  gemm128<<<dim3(99, 6), blk, 0, stream>>>(
      dec_bf, Wqkv1, Bqkv1, nullptr, nullptr, qkv1, M, 768, 256, 0);
  attn_mfma<<<dim3(512, 2), blk, 0, stream>>>(
      qkv1, 768, qkv1 + 256, 768, qkv1 + 512, 768, mones, o1);
  gemm128<<<dim3(99, 2), blk, 0, stream>>>(
      o1, Wo1, a1_bo, dec_in, t_buf, nullptr, M, 256, 256, 0);
  ln_kernel<<<M / 4, blk, 0, stream>>>(t_buf, ln1_g, ln1_b, x1, nullptr);

  // ---- attention 2: q=k=e, v=dec_in, mask ----
  gemm128<<<dim3(99, 4), blk, 0, stream>>>(
      e_bf, Wqk2, Bqk2, nullptr, nullptr, qk2, M, 512, 256, 0);
  gemm128<<<dim3(99, 2), blk, 0, stream>>>(
      dec_bf, Wv2, a2_bv, nullptr, nullptr, v2, M, 256, 256, 0);
  attn_mfma<<<dim3(512, 2), blk, 0, stream>>>(
      qk2, 512, qk2 + 256, 512, v2, 256, mbits, o2);
  gemm128<<<dim3(99, 2), blk, 0, stream>>>(
      o2, Wo2, a2_bo, x1, t_buf, nullptr, M, 256, 256, 0);
  ln_kernel<<<M / 4, blk, 0, stream>>>(t_buf, ln2_g, ln2_b, x2, x2b);

  // ---- feed-forward ----
  gemm128<<<dim3(99, 8), blk, 0, stream>>>(
      x2b, Wff1, ff_b1, nullptr, nullptr, h_buf, M, FFDIM, 256, 1);
  gemm128<<<dim3(99, 2), blk, 0, stream>>>(
      h_buf, Wff2, ff_b2, x2, t_buf, nullptr, M, 256, 1024, 0);
  ln_kernel<<<M / 4, blk, 0, stream>>>(t_buf, ln3_g, ln3_b, (float*)d_out, nullptr);
}

// Round 5
// 357.955 us; speedup vs baseline: 1.3545x; 1.3545x over previous
//
#include <hip/hip_runtime.h>
#include <hip/hip_bf16.h>
#include <math.h>

#define DMODEL 256
#define NH 8
#define DKH 32
#define SEQ 197
#define BATCH 64
#define NPAT 196
#define FFDIM 1024
#define KCONV 768
#define EPSLN 1e-5f
#define MROWS (BATCH * SEQ)  // 12608 = 197*64
#define SP 224               // SEQ padded to 7 super-tiles of 32

typedef __attribute__((ext_vector_type(8))) short short8;
typedef __attribute__((ext_vector_type(4))) short short4v;
typedef __attribute__((ext_vector_type(4))) float floatx4;

__device__ inline short f2b(float f) {
  unsigned u = __float_as_uint(f);
  unsigned r = (u + 0x7FFFu + ((u >> 16) & 1u)) >> 16;
  return (short)r;
}
__device__ inline float b2f(short s) {
  return __uint_as_float(((unsigned)(unsigned short)s) << 16);
}

// async global->LDS 16B DMA (lds dest must be wave-uniform base + lane*16)
typedef const __attribute__((address_space(1))) unsigned int gu32;
typedef __attribute__((address_space(3))) unsigned int lu32;
__device__ __forceinline__ void gl_lds16(const void* g, void* l) {
  __builtin_amdgcn_global_load_lds((gu32*)g, (lu32*)l, 16, 0, 0);
}

// ---------------------------------------------------------------------------
// fp32 -> bf16 convert of dec_in
// ---------------------------------------------------------------------------
__global__ __launch_bounds__(256) void convert_dec(
    const float* __restrict__ dec, short* __restrict__ dec_bf)
{
  const int ND = (MROWS * DMODEL) / 8;  // 403456
  int i = blockIdx.x * 256 + threadIdx.x;
  if (i >= ND) return;
  float4 a0 = ((const float4*)dec)[i * 2];
  float4 a1 = ((const float4*)dec)[i * 2 + 1];
  short8 o;
  o[0] = f2b(a0.x); o[1] = f2b(a0.y); o[2] = f2b(a0.z); o[3] = f2b(a0.w);
  o[4] = f2b(a1.x); o[5] = f2b(a1.y); o[6] = f2b(a1.z); o[7] = f2b(a1.w);
  ((short8*)dec_bf)[i] = o;
}

// ---------------------------------------------------------------------------
// One-shot weight prep: fp32 -> bf16, with QKV / QK concatenation.
// ---------------------------------------------------------------------------
__global__ __launch_bounds__(256) void prep_weights(
    const float* wq1, const float* wk1, const float* wv1,
    const float* bq1, const float* bk1, const float* bv1,
    const float* wq2, const float* wk2, const float* bq2, const float* bk2,
    const float* wv2s, const float* wo1, const float* wo2,
    const float* ffw1, const float* ffw2, const float* convw,
    short* Wqkv1, float* Bqkv1, short* Wqk2, float* Bqk2,
    short* Wv2, short* Wo1, short* Wo2, short* Wff1, short* Wff2, short* Wconv)
{
  int i = blockIdx.x * 256 + threadIdx.x;
  if (i < 65536) {
    Wqkv1[i] = f2b(wq1[i]); Wqkv1[65536 + i] = f2b(wk1[i]); Wqkv1[131072 + i] = f2b(wv1[i]);
    Wqk2[i] = f2b(wq2[i]);  Wqk2[65536 + i] = f2b(wk2[i]);
    Wv2[i] = f2b(wv2s[i]);  Wo1[i] = f2b(wo1[i]);  Wo2[i] = f2b(wo2[i]);
  }
  if (i < 262144) { Wff1[i] = f2b(ffw1[i]); Wff2[i] = f2b(ffw2[i]); }
  if (i < 196608) { Wconv[i] = f2b(convw[i]); }
  if (i < 256) {
    Bqkv1[i] = bq1[i]; Bqkv1[256 + i] = bk1[i]; Bqkv1[512 + i] = bv1[i];
    Bqk2[i] = bq2[i];  Bqk2[256 + i] = bk2[i];
  }
}

// Pack mask (S,S) int32 -> per-row 4x uint64 bitmask; plus all-ones table.
__global__ void mask_pack(const int* __restrict__ mask,
                          unsigned long long* __restrict__ bits,
                          unsigned long long* __restrict__ ones)
{
  int idx = blockIdx.x * 256 + threadIdx.x;
  if (idx >= SEQ * 4) return;
  int r = idx >> 2, w = idx & 3;
  unsigned long long bb = 0ull, oo = 0ull;
  for (int j = 0; j < 64; j++) {
    int c = w * 64 + j;
    if (c < SEQ) {
      oo |= (1ull << j);
      if (mask[r * SEQ + c] != 0) bb |= (1ull << j);
    }
  }
  bits[idx] = bb;
  ones[idx] = oo;
}

// cls row (196, appended at END) + pos -> bf16 e
__global__ void cls_kernel(const float* __restrict__ cls, const float* __restrict__ pos,
                           short* __restrict__ e)
{
  int b = blockIdx.x, d = threadIdx.x;
  e[((size_t)b * SEQ + NPAT) * DMODEL + d] = f2b(cls[d] + pos[NPAT * DMODEL + d]);
}

// ---------------------------------------------------------------------------
// 64x64-tile bf16 MFMA GEMM, BK=64: C = A @ W^T (+bias)(+res bf16)(+relu).
// A,W bf16 row-major. global_load_lds staging, global-side XOR chunk swizzle
// (8 chunks of 16B per 64-elem row; chunk' = chunk ^ (row&7)).
// 4 waves, each 32x32 via 2x2 mfma_f32_16x16x32_bf16, 2 k-substeps.
// High block count (grid.x = M/64) => 3-8 blocks/CU for latency hiding.
// ---------------------------------------------------------------------------
__global__ __launch_bounds__(256) void gemm64(
    const short* __restrict__ A, const short* __restrict__ W,
    const float* __restrict__ bias, const short* __restrict__ res,
    float* __restrict__ outf, short* __restrict__ outb,
    int M, int N, int K, int relu)
{
  __shared__ short Al[64 * 64];
  __shared__ short Bl[64 * 64];
  int m0 = blockIdx.x * 64, n0 = blockIdx.y * 64;
  int t = threadIdx.x;
  int wave = t >> 6, lane = t & 63;
  int wm = (wave & 1) * 32, wn = (wave >> 1) * 32;
  int ml = lane & 15, quad = lane >> 4;
  int m7 = ml & 7;

  // staging: slot s = p*256+t -> LDS row s>>3, lds-chunk s&7 at offset s*16B;
  // global chunk fetched = (s&7) ^ (row&7)  (rows r and r+32 share &7)
  int rs = t >> 3;
  int cs = (t & 7) ^ (rs & 7);
  const short* gA0 = A + (size_t)(m0 + rs) * K + cs * 8;
  const short* gA1 = A + (size_t)(m0 + rs + 32) * K + cs * 8;
  const short* gB0 = W + (size_t)(n0 + rs) * K + cs * 8;
  const short* gB1 = W + (size_t)(n0 + rs + 32) * K + cs * 8;
  short* lA0 = &Al[t * 8];
  short* lA1 = &Al[t * 8 + 2048];
  short* lB0 = &Bl[t * 8];
  short* lB1 = &Bl[t * 8 + 2048];

  // fragment read offsets (shorts): row*64 + ((kk*4+quad)^ (row&7))*8
  int offA[2][2], offB[2][2];
#pragma unroll
  for (int kk = 0; kk < 2; kk++)
#pragma unroll
    for (int i = 0; i < 2; i++) {
      int ra = wm + i * 16 + ml;
      offA[kk][i] = ra * 64 + (((kk * 4 + quad) ^ m7) * 8);
      int rb = wn + i * 16 + ml;
      offB[kk][i] = rb * 64 + (((kk * 4 + quad) ^ m7) * 8);
    }

  floatx4 z = {0.f, 0.f, 0.f, 0.f};
  floatx4 acc[2][2] = {{z, z}, {z, z}};

  for (int k0 = 0; k0 < K; k0 += 64) {
    __syncthreads();
    gl_lds16(gA0 + k0, lA0);
    gl_lds16(gA1 + k0, lA1);
    gl_lds16(gB0 + k0, lB0);
    gl_lds16(gB1 + k0, lB1);
    __builtin_amdgcn_s_waitcnt(0x0F70);  // vmcnt(0)
    __syncthreads();
#pragma unroll
    for (int kk = 0; kk < 2; kk++) {
      short8 a0 = *(const short8*)&Al[offA[kk][0]];
      short8 a1 = *(const short8*)&Al[offA[kk][1]];
      short8 b0 = *(const short8*)&Bl[offB[kk][0]];
      short8 b1 = *(const short8*)&Bl[offB[kk][1]];
      acc[0][0] = __builtin_amdgcn_mfma_f32_16x16x32_bf16(a0, b0, acc[0][0], 0, 0, 0);
      acc[0][1] = __builtin_amdgcn_mfma_f32_16x16x32_bf16(a0, b1, acc[0][1], 0, 0, 0);
      acc[1][0] = __builtin_amdgcn_mfma_f32_16x16x32_bf16(a1, b0, acc[1][0], 0, 0, 0);
      acc[1][1] = __builtin_amdgcn_mfma_f32_16x16x32_bf16(a1, b1, acc[1][1], 0, 0, 0);
    }
  }
#pragma unroll
  for (int i = 0; i < 2; i++)
#pragma unroll
    for (int j = 0; j < 2; j++)
#pragma unroll
      for (int rr = 0; rr < 4; rr++) {
        int row = m0 + wm + i * 16 + quad * 4 + rr;
        int col = n0 + wn + j * 16 + ml;
        float v = acc[i][j][rr] + bias[col];
        if (res) v += b2f(res[(size_t)row * N + col]);
        if (relu) v = fmaxf(v, 0.f);
        if (outf) outf[(size_t)row * N + col] = v;
        if (outb) outb[(size_t)row * N + col] = f2b(v);
      }
}

// ---------------------------------------------------------------------------
// Patch-embed conv as 64x64 MFMA GEMM, BK=64, im2col directly from fp32 img
// (VGPR staging + f2b, LDS-side swizzle). M=12544=196*64, K=768, N=256.
// Epilogue: +conv_b+pos -> bf16 e at rows (b*197+p).
// ---------------------------------------------------------------------------
__global__ __launch_bounds__(256) void conv64(
    const float* __restrict__ img, const short* __restrict__ W,
    const float* __restrict__ cb, const float* __restrict__ pos,
    short* __restrict__ e)
{
  __shared__ short Al[64 * 64];
  __shared__ short Bl[64 * 64];
  int m0 = blockIdx.x * 64, n0 = blockIdx.y * 64;
  int t = threadIdx.x;
  int wave = t >> 6, lane = t & 63;
  int wm = (wave & 1) * 32, wn = (wave >> 1) * 32;
  int ml = lane & 15, quad = lane >> 4;
  int m7 = ml & 15 & 7;

  // A staging (fp32 -> bf16): slot s = p*256+t; row = (t>>3)+p*32; chunk cg = t&7
  int rA = t >> 3, cg = t & 7;
  int pr_off = cg >> 1;          // patch-row within the 4-row K-group
  int px_off = (cg & 1) * 8;     // 0 or 8 pixels
  int csw = cg ^ (rA & 7);       // LDS-side swizzled chunk (same for p=0,1)
  const float* baseA[2];
  short* lA[2];
#pragma unroll
  for (int p = 0; p < 2; p++) {
    int m = m0 + rA + p * 32;
    int b = m / NPAT, pp = m - b * NPAT;
    int py = pp / 14, px = pp - py * 14;
    baseA[p] = img + (size_t)b * 3 * 50176 + (size_t)(py * 16) * 224 + px * 16 + px_off;
    lA[p] = &Al[(rA + p * 32) * 64 + csw * 8];
  }
  // B staging via gl_lds16 (weights bf16), global-side swizzle
  int rs = t >> 3;
  int cs = (t & 7) ^ (rs & 7);
  const short* gB0 = W + (size_t)(n0 + rs) * KCONV + cs * 8;
  const short* gB1 = W + (size_t)(n0 + rs + 32) * KCONV + cs * 8;
  short* lB0 = &Bl[t * 8];
  short* lB1 = &Bl[t * 8 + 2048];

  int offA[2][2], offB[2][2];
#pragma unroll
  for (int kk = 0; kk < 2; kk++)
#pragma unroll
    for (int i = 0; i < 2; i++) {
      int ra = wm + i * 16 + ml;
      offA[kk][i] = ra * 64 + (((kk * 4 + quad) ^ m7) * 8);
      int rb = wn + i * 16 + ml;
      offB[kk][i] = rb * 64 + (((kk * 4 + quad) ^ m7) * 8);
    }

  floatx4 z = {0.f, 0.f, 0.f, 0.f};
  floatx4 acc[2][2] = {{z, z}, {z, z}};

  for (int k0 = 0; k0 < KCONV; k0 += 64) {
    int ch = k0 >> 8;
    int rr0 = (k0 & 255) >> 4;
    __syncthreads();
    gl_lds16(gB0 + k0, lB0);
    gl_lds16(gB1 + k0, lB1);
#pragma unroll
    for (int p = 0; p < 2; p++) {
      const float* ap = baseA[p] + (size_t)ch * 50176 + (rr0 + pr_off) * 224;
      float4 a0 = *(const float4*)ap;
      float4 a1 = *(const float4*)(ap + 4);
      short8 av;
      av[0] = f2b(a0.x); av[1] = f2b(a0.y); av[2] = f2b(a0.z); av[3] = f2b(a0.w);
      av[4] = f2b(a1.x); av[5] = f2b(a1.y); av[6] = f2b(a1.z); av[7] = f2b(a1.w);
      *(short8*)lA[p] = av;
    }
    __builtin_amdgcn_s_waitcnt(0x0F70);  // vmcnt(0); syncthreads covers lgkm
    __syncthreads();
#pragma unroll
    for (int kk = 0; kk < 2; kk++) {
      short8 a0 = *(const short8*)&Al[offA[kk][0]];
      short8 a1 = *(const short8*)&Al[offA[kk][1]];
      short8 b0 = *(const short8*)&Bl[offB[kk][0]];
      short8 b1 = *(const short8*)&Bl[offB[kk][1]];
      acc[0][0] = __builtin_amdgcn_mfma_f32_16x16x32_bf16(a0, b0, acc[0][0], 0, 0, 0);
      acc[0][1] = __builtin_amdgcn_mfma_f32_16x16x32_bf16(a0, b1, acc[0][1], 0, 0, 0);
      acc[1][0] = __builtin_amdgcn_mfma_f32_16x16x32_bf16(a1, b0, acc[1][0], 0, 0, 0);
      acc[1][1] = __builtin_amdgcn_mfma_f32_16x16x32_bf16(a1, b1, acc[1][1], 0, 0, 0);
    }
  }
#pragma unroll
  for (int i = 0; i < 2; i++)
#pragma unroll
    for (int j = 0; j < 2; j++)
#pragma unroll
      for (int rr = 0; rr < 4; rr++) {
        int mrow = m0 + wm + i * 16 + quad * 4 + rr;
        int b2 = mrow / NPAT, p2 = mrow - b2 * NPAT;
        int col = n0 + wn + j * 16 + ml;
        e[((size_t)b2 * SEQ + p2) * DMODEL + col] =
            f2b(acc[i][j][rr] + cb[col] + pos[p2 * DMODEL + col]);
      }
}

// ---------------------------------------------------------------------------
// MFMA flash attention, S^T formulation. Grid (B*NH, 2); 4 waves/block;
// each wave processes 2 sequential 16-query tiles.
// ---------------------------------------------------------------------------
__global__ __launch_bounds__(256) void attn_mfma(
    const short* __restrict__ qp, int qstr,
    const short* __restrict__ kp, int kstr,
    const short* __restrict__ vp, int vstr,
    const unsigned long long* __restrict__ mbits,
    short* __restrict__ op)
{
  __shared__ short ks[SP][40];
  __shared__ short vt[DKH][SP + 8];
  __shared__ short ps[4][16][40];
  int bh = blockIdx.x;
  int b = bh >> 3, h = bh & 7;
  int t = threadIdx.x;
  int wave = t >> 6, lane = t & 63;
  int ml = lane & 15, quad = lane >> 4;

  const short* kb = kp + (size_t)b * SEQ * kstr + h * DKH;
  const short* vb = vp + (size_t)b * SEQ * vstr + h * DKH;
  for (int idx = t; idx < SEQ * 4; idx += 256) {
    int s = idx >> 2, c = (idx & 3) * 8;
    *(short8*)&ks[s][c] = *(const short8*)(kb + (size_t)s * kstr + c);
  }
  for (int idx = t; idx < SEQ * 4; idx += 256) {
    int s = idx >> 2, c = (idx & 3) * 8;
    short8 v8 = *(const short8*)(vb + (size_t)s * vstr + c);
#pragma unroll
    for (int j = 0; j < 8; j++) vt[c + j][s] = v8[j];
  }
  for (int idx = t; idx < DKH * (SP - SEQ); idx += 256) {
    int d = idx / (SP - SEQ), j = SEQ + idx - d * (SP - SEQ);
    vt[d][j] = 0;
  }
  __syncthreads();

  const float scale = 0.17677669529663687f;  // 1/sqrt(32)
  floatx4 z = {0.f, 0.f, 0.f, 0.f};

  for (int tt = 0; tt < 2; tt++) {
    int ti = blockIdx.y * 8 + wave * 2 + tt;
    int q0 = ti * 16;
    if (q0 >= SEQ) continue;
    int qrow = q0 + ml;
    int qc = qrow < SEQ ? qrow : SEQ - 1;
    short8 qf = *(const short8*)(qp + ((size_t)b * SEQ + qc) * qstr + h * DKH + quad * 8);
    const unsigned long long* mrow = mbits + (size_t)qc * 4;

    floatx4 accO0 = z, accO1 = z;
    float mrun = -1e30f, lrun = 0.f;

    for (int st = 0; st < 7; st++) {
      int j0 = st * 32;
      short8 k0 = *(const short8*)&ks[j0 + ml][quad * 8];
      short8 k1 = *(const short8*)&ks[j0 + 16 + ml][quad * 8];
      floatx4 s0 = __builtin_amdgcn_mfma_f32_16x16x32_bf16(k0, qf, z, 0, 0, 0);
      floatx4 s1 = __builtin_amdgcn_mfma_f32_16x16x32_bf16(k1, qf, z, 0, 0, 0);
      unsigned long long mb = mrow[j0 >> 6] >> (j0 & 63);
      float sv[8];
#pragma unroll
      for (int r = 0; r < 4; r++) {
        int jl = quad * 4 + r;
        sv[r]     = ((mb >> jl) & 1ull)        ? s0[r] * scale : -1e38f;
        sv[4 + r] = ((mb >> (16 + jl)) & 1ull) ? s1[r] * scale : -1e38f;
      }
      float tm = sv[0];
#pragma unroll
      for (int i = 1; i < 8; i++) tm = fmaxf(tm, sv[i]);
      tm = fmaxf(tm, __shfl_xor(tm, 16));
      tm = fmaxf(tm, __shfl_xor(tm, 32));
      float nm = fmaxf(mrun, tm);
      float alpha = __expf(mrun - nm);
      float pv[8];
      float psum = 0.f;
#pragma unroll
      for (int i = 0; i < 8; i++) { pv[i] = __expf(sv[i] - nm); psum += pv[i]; }
      psum += __shfl_xor(psum, 16);
      psum += __shfl_xor(psum, 32);
      lrun = lrun * alpha + psum;
      mrun = nm;
      accO0 = accO0 * alpha;
      accO1 = accO1 * alpha;
      short4v p0, p1;
#pragma unroll
      for (int r = 0; r < 4; r++) { p0[r] = f2b(pv[r]); p1[r] = f2b(pv[4 + r]); }
      *(short4v*)&ps[wave][ml][quad * 4]      = p0;
      *(short4v*)&ps[wave][ml][16 + quad * 4] = p1;
      __asm__ volatile("s_waitcnt lgkmcnt(0)" ::: "memory");  // wave-local RAW
      short8 pf = *(const short8*)&ps[wave][ml][quad * 8];
      short8 vf0 = *(const short8*)&vt[ml][j0 + quad * 8];
      short8 vf1 = *(const short8*)&vt[16 + ml][j0 + quad * 8];
      accO0 = __builtin_amdgcn_mfma_f32_16x16x32_bf16(vf0, pf, accO0, 0, 0, 0);
      accO1 = __builtin_amdgcn_mfma_f32_16x16x32_bf16(vf1, pf, accO1, 0, 0, 0);
    }
    if (qrow < SEQ) {
      float inv = 1.f / lrun;
      short* ob = op + ((size_t)b * SEQ + qrow) * DMODEL + h * DKH;
      short4v o0, o1;
#pragma unroll
      for (int r = 0; r < 4; r++) {
        o0[r] = f2b(accO0[r] * inv);
        o1[r] = f2b(accO1[r] * inv);
      }
      *(short4v*)(ob + quad * 4)      = o0;
      *(short4v*)(ob + 16 + quad * 4) = o1;
    }
  }
}

// ---------------------------------------------------------------------------
// LayerNorm over D=256 from bf16 input, one wave per row (4 rows/block).
// Writes optional fp32 and/or bf16 outputs.
// ---------------------------------------------------------------------------
__global__ __launch_bounds__(256) void ln_bf(
    const short* __restrict__ x, const float* __restrict__ g,
    const float* __restrict__ bt, float* __restrict__ outf,
    short* __restrict__ outb)
{
  int wave = threadIdx.x >> 6, lane = threadIdx.x & 63;
  int row = blockIdx.x * 4 + wave;
  short4v xv = *(const short4v*)(x + (size_t)row * DMODEL + lane * 4);
  float v0 = b2f(xv[0]), v1 = b2f(xv[1]), v2 = b2f(xv[2]), v3 = b2f(xv[3]);
  float s = v0 + v1 + v2 + v3;
  for (int off = 32; off; off >>= 1) s += __shfl_down(s, off);
  s = __shfl(s, 0);
  float mean = s * (1.0f / DMODEL);
  float d0 = v0 - mean, d1 = v1 - mean, d2 = v2 - mean, d3 = v3 - mean;
  float vv = d0 * d0 + d1 * d1 + d2 * d2 + d3 * d3;
  for (int off = 32; off; off >>= 1) vv += __shfl_down(vv, off);
  vv = __shfl(vv, 0);
  float inv = rsqrtf(vv * (1.0f / DMODEL) + EPSLN);
  float4 gg = *(const float4*)(g + lane * 4);
  float4 bb = *(const float4*)(bt + lane * 4);
  float r0 = d0 * inv * gg.x + bb.x;
  float r1 = d1 * inv * gg.y + bb.y;
  float r2 = d2 * inv * gg.z + bb.z;
  float r3 = d3 * inv * gg.w + bb.w;
  if (outf) {
    float4 o = {r0, r1, r2, r3};
    *(float4*)(outf + (size_t)row * DMODEL + lane * 4) = o;
  }
  if (outb) {
    short4v o;
    o[0] = f2b(r0); o[1] = f2b(r1); o[2] = f2b(r2); o[3] = f2b(r3);
    *(short4v*)(outb + (size_t)row * DMODEL + lane * 4) = o;
  }
}

// ---------------------------------------------------------------------------
extern "C" void kernel_launch(void* const* d_in, const int* in_sizes, int n_in,
                              void* d_out, int out_size, void* d_ws, size_t ws_size,
                              hipStream_t stream)
{
  const float* enc    = (const float*)d_in[0];
  const float* dec_in = (const float*)d_in[1];
  const int*   mask   = (const int*)  d_in[2];
  const float* conv_w = (const float*)d_in[3];
  const float* conv_b = (const float*)d_in[4];
  const float* cls    = (const float*)d_in[5];
  const float* pos    = (const float*)d_in[6];
  const float* ff_w1  = (const float*)d_in[7];
  const float* ff_b1  = (const float*)d_in[8];
  const float* ff_w2  = (const float*)d_in[9];
  const float* ff_b2  = (const float*)d_in[10];
  const float* ln1_g  = (const float*)d_in[11];
  const float* ln1_b  = (const float*)d_in[12];
  const float* ln2_g  = (const float*)d_in[13];
  const float* ln2_b  = (const float*)d_in[14];
  const float* ln3_g  = (const float*)d_in[15];
  const float* ln3_b  = (const float*)d_in[16];
  const float* a1_wq = (const float*)d_in[17]; const float* a1_bq = (const float*)d_in[18];
  const float* a1_wk = (const float*)d_in[19]; const float* a1_bk = (const float*)d_in[20];
  const float* a1_wv = (const float*)d_in[21]; const float* a1_bv = (const float*)d_in[22];
  const float* a1_wo = (const float*)d_in[23]; const float* a1_bo = (const float*)d_in[24];
  const float* a2_wq = (const float*)d_in[25]; const float* a2_bq = (const float*)d_in[26];
  const float* a2_wk = (const float*)d_in[27]; const float* a2_bk = (const float*)d_in[28];
  const float* a2_wv = (const float*)d_in[29]; const float* a2_bv = (const float*)d_in[30];
  const float* a2_wo = (const float*)d_in[31]; const float* a2_bo = (const float*)d_in[32];

  // ---- workspace layout ----
  char* wsB = (char*)d_ws;
  short* Wqkv1 = (short*)wsB;            // 196608 shorts
  short* Wqk2  = Wqkv1 + 196608;         // 131072
  short* Wv2   = Wqk2 + 131072;          // 65536
  short* Wo1   = Wv2 + 65536;            // 65536
  short* Wo2   = Wo1 + 65536;            // 65536
  short* Wff1  = Wo2 + 65536;            // 262144
  short* Wff2  = Wff1 + 262144;          // 262144
  short* Wconv = Wff2 + 262144;          // 196608
  float* Bqkv1 = (float*)(Wconv + 196608);
  float* Bqk2  = Bqkv1 + 768;
  unsigned long long* mbits = (unsigned long long*)(Bqk2 + 512);  // 788 u64
  unsigned long long* mones = mbits + 788;                        // 788 u64

  const size_t MB = 1048576;
  short* dec_bf = (short*)(wsB + 3 * MB);    //  6.46 MB
  short* e_bf   = (short*)(wsB + 10 * MB);   //  6.46 MB
  short* qkv1   = (short*)(wsB + 17 * MB);   // 19.37 MB
  short* o1     = (short*)(wsB + 37 * MB);   //  6.46 MB
  short* qk2    = (short*)(wsB + 44 * MB);   // 12.91 MB
  short* v2     = (short*)(wsB + 57 * MB);   //  6.46 MB
  short* h_buf  = (short*)(wsB + 64 * MB);   // 25.82 MB
  short* t_bf   = (short*)(wsB + 90 * MB);   //  6.46 MB
  short* x1b    = (short*)(wsB + 97 * MB);   //  6.46 MB
  short* x2b    = (short*)(wsB + 104 * MB);  //  6.46 MB
  short* o2     = o1;

  dim3 blk(256);
  const int M = MROWS;

  convert_dec<<<1576, blk, 0, stream>>>(dec_in, dec_bf);
  prep_weights<<<1024, blk, 0, stream>>>(
      a1_wq, a1_wk, a1_wv, a1_bq, a1_bk, a1_bv,
      a2_wq, a2_wk, a2_bq, a2_bk, a2_wv, a1_wo, a2_wo,
      ff_w1, ff_w2, conv_w,
      Wqkv1, Bqkv1, Wqk2, Bqk2, Wv2, Wo1, Wo2, Wff1, Wff2, Wconv);
  mask_pack<<<4, blk, 0, stream>>>(mask, mbits, mones);

  // patch embed -> bf16 e
  conv64<<<dim3(196, 4), blk, 0, stream>>>(enc, Wconv, conv_b, pos, e_bf);
  cls_kernel<<<BATCH, DMODEL, 0, stream>>>(cls, pos, e_bf);

  // ---- attention 1: q=k=v=dec_in, no mask ----
  gemm64<<<dim3(197, 12), blk, 0, stream>>>(
      dec_bf, Wqkv1, Bqkv1, nullptr, nullptr, qkv1, M, 768, 256, 0);
  attn_mfma<<<dim3(512, 2), blk, 0, stream>>>(
      qkv1, 768, qkv1 + 256, 768, qkv1 + 512, 768, mones, o1);
  gemm64<<<dim3(197, 4), blk, 0, stream>>>(
      o1, Wo1, a1_bo, dec_bf, nullptr, t_bf, M, 256, 256, 0);
  ln_bf<<<M / 4, blk, 0, stream>>>(t_bf, ln1_g, ln1_b, nullptr, x1b);

  // ---- attention 2: q=k=e, v=dec_in, mask ----
  gemm64<<<dim3(197, 8), blk, 0, stream>>>(
      e_bf, Wqk2, Bqk2, nullptr, nullptr, qk2, M, 512, 256, 0);
  gemm64<<<dim3(197, 4), blk, 0, stream>>>(
      dec_bf, Wv2, a2_bv, nullptr, nullptr, v2, M, 256, 256, 0);
  attn_mfma<<<dim3(512, 2), blk, 0, stream>>>(
      qk2, 512, qk2 + 256, 512, v2, 256, mbits, o2);
  gemm64<<<dim3(197, 4), blk, 0, stream>>>(
      o2, Wo2, a2_bo, x1b, nullptr, t_bf, M, 256, 256, 0);
  ln_bf<<<M / 4, blk, 0, stream>>>(t_bf, ln2_g, ln2_b, nullptr, x2b);

  // ---- feed-forward ----
  gemm64<<<dim3(197, 16), blk, 0, stream>>>(
      x2b, Wff1, ff_b1, nullptr, nullptr, h_buf, M, FFDIM, 256, 1);
  gemm64<<<dim3(197, 4), blk, 0, stream>>>(
      h_buf, Wff2, ff_b2, x2b, nullptr, t_bf, M, 256, 1024, 0);
  ln_bf<<<M / 4, blk, 0, stream>>>(t_bf, ln3_g, ln3_b, (float*)d_out, nullptr);
}

// Round 6
// 333.756 us; speedup vs baseline: 1.4527x; 1.0725x over previous
//
#include <hip/hip_runtime.h>
#include <hip/hip_bf16.h>
#include <math.h>

#define DMODEL 256
#define NH 8
#define DKH 32
#define SEQ 197
#define BATCH 64
#define NPAT 196
#define FFDIM 1024
#define KCONV 768
#define EPSLN 1e-5f
#define MROWS (BATCH * SEQ)  // 12608 = 197*64
#define SP 224               // SEQ padded to 7 super-tiles of 32

typedef __attribute__((ext_vector_type(8))) short short8;
typedef __attribute__((ext_vector_type(4))) short short4v;
typedef __attribute__((ext_vector_type(4))) float floatx4;

__device__ inline short f2b(float f) {
  unsigned u = __float_as_uint(f);
  unsigned r = (u + 0x7FFFu + ((u >> 16) & 1u)) >> 16;
  return (short)r;
}
__device__ inline float b2f(short s) {
  return __uint_as_float(((unsigned)(unsigned short)s) << 16);
}

// async global->LDS 16B DMA (lds dest: wave-uniform base + lane*16)
typedef const __attribute__((address_space(1))) unsigned int gu32;
typedef __attribute__((address_space(3))) unsigned int lu32;
__device__ __forceinline__ void gl_lds16(const void* g, void* l) {
  __builtin_amdgcn_global_load_lds((gu32*)g, (lu32*)l, 16, 0, 0);
}

// ---------------------------------------------------------------------------
// Pipelined 64x64 bf16 MFMA GEMM body, BK=64, double-buffered LDS.
// Prefetch tile k+1 before waiting vmcnt(4) for tile k; raw s_barrier
// (no __syncthreads) so the compiler can't force a vmcnt(0) drain.
// ---------------------------------------------------------------------------
__device__ __forceinline__ void gemm64_body(
    char* smem, int bx, int by,
    const short* __restrict__ A, const short* __restrict__ W,
    const float* __restrict__ bias, const short* __restrict__ resb,
    float* __restrict__ outf, short* __restrict__ outb,
    int N, int K, int relu)
{
  short* Al = (short*)smem;            // 2 x 4096 shorts
  short* Bl = (short*)(smem + 16384);  // 2 x 4096 shorts
  const int t = threadIdx.x;
  const int wave = t >> 6, lane = t & 63;
  const int wm = (wave & 1) * 32, wn = (wave >> 1) * 32;
  const int ml = lane & 15, quad = lane >> 4;
  const int m7 = ml & 7;
  const int m0 = bx * 64, n0 = by * 64;

  // staging: LDS slot s = p*256+t -> row s>>3, lds-chunk s&7;
  // global chunk = (s&7) ^ (row&7)
  const int rs = t >> 3;
  const int cs = (t & 7) ^ (rs & 7);
  const short* gA0 = A + (size_t)(m0 + rs) * K + cs * 8;
  const short* gA1 = A + (size_t)(m0 + rs + 32) * K + cs * 8;
  const short* gB0 = W + (size_t)(n0 + rs) * K + cs * 8;
  const short* gB1 = W + (size_t)(n0 + rs + 32) * K + cs * 8;

  int offA[2][2], offB[2][2];
#pragma unroll
  for (int kk = 0; kk < 2; kk++)
#pragma unroll
    for (int i = 0; i < 2; i++) {
      int ra = wm + i * 16 + ml;
      offA[kk][i] = ra * 64 + (((kk * 4 + quad) ^ m7) * 8);
      int rb = wn + i * 16 + ml;
      offB[kk][i] = rb * 64 + (((kk * 4 + quad) ^ m7) * 8);
    }

  floatx4 z = {0.f, 0.f, 0.f, 0.f};
  floatx4 acc[2][2] = {{z, z}, {z, z}};

  const int niter = K >> 6;
  gl_lds16(gA0, Al + t * 8);
  gl_lds16(gA1, Al + t * 8 + 2048);
  gl_lds16(gB0, Bl + t * 8);
  gl_lds16(gB1, Bl + t * 8 + 2048);
  for (int k = 0; k < niter; k++) {
    int cur = k & 1;
    if (k + 1 < niter) {
      int nb = (cur ^ 1) * 4096;
      int k0 = (k + 1) << 6;
      gl_lds16(gA0 + k0, Al + nb + t * 8);
      gl_lds16(gA1 + k0, Al + nb + t * 8 + 2048);
      gl_lds16(gB0 + k0, Bl + nb + t * 8);
      gl_lds16(gB1 + k0, Bl + nb + t * 8 + 2048);
      __builtin_amdgcn_s_waitcnt(0x0F74);  // vmcnt(4): cur's loads done
    } else {
      __builtin_amdgcn_s_waitcnt(0x0F70);  // vmcnt(0)
    }
    __asm__ volatile("s_barrier" ::: "memory");
    const short* Ac = Al + cur * 4096;
    const short* Bc = Bl + cur * 4096;
#pragma unroll
    for (int kk = 0; kk < 2; kk++) {
      short8 a0 = *(const short8*)&Ac[offA[kk][0]];
      short8 a1 = *(const short8*)&Ac[offA[kk][1]];
      short8 b0 = *(const short8*)&Bc[offB[kk][0]];
      short8 b1 = *(const short8*)&Bc[offB[kk][1]];
      acc[0][0] = __builtin_amdgcn_mfma_f32_16x16x32_bf16(a0, b0, acc[0][0], 0, 0, 0);
      acc[0][1] = __builtin_amdgcn_mfma_f32_16x16x32_bf16(a0, b1, acc[0][1], 0, 0, 0);
      acc[1][0] = __builtin_amdgcn_mfma_f32_16x16x32_bf16(a1, b0, acc[1][0], 0, 0, 0);
      acc[1][1] = __builtin_amdgcn_mfma_f32_16x16x32_bf16(a1, b1, acc[1][1], 0, 0, 0);
    }
    __asm__ volatile("s_barrier" ::: "memory");  // reads done before overwrite
  }
#pragma unroll
  for (int i = 0; i < 2; i++)
#pragma unroll
    for (int j = 0; j < 2; j++)
#pragma unroll
      for (int rr = 0; rr < 4; rr++) {
        int row = m0 + wm + i * 16 + quad * 4 + rr;
        int col = n0 + wn + j * 16 + ml;
        float v = acc[i][j][rr] + bias[col];
        if (resb) v += b2f(resb[(size_t)row * N + col]);
        if (relu) v = fmaxf(v, 0.f);
        if (outf) outf[(size_t)row * N + col] = v;
        if (outb) outb[(size_t)row * N + col] = f2b(v);
      }
}

// ---------------------------------------------------------------------------
// Patch-embed conv as 64x64 MFMA GEMM body, BK=64, im2col from fp32 img
// (VGPR f2b staging, LDS-side swizzle). Single-buffered (runs fused with
// qkv1/v2 GEMMs which provide the latency hiding). Uses 16 KB of smem.
// ---------------------------------------------------------------------------
__device__ __forceinline__ void conv64_body(
    char* smem, int bx, int by,
    const float* __restrict__ img, const short* __restrict__ W,
    const float* __restrict__ cb, const float* __restrict__ pos,
    short* __restrict__ e)
{
  short* Al = (short*)smem;           // 4096 shorts
  short* Bl = (short*)(smem + 8192);  // 4096 shorts
  const int t = threadIdx.x;
  const int wave = t >> 6, lane = t & 63;
  const int wm = (wave & 1) * 32, wn = (wave >> 1) * 32;
  const int ml = lane & 15, quad = lane >> 4;
  const int m7 = ml & 7;
  const int m0 = bx * 64, n0 = by * 64;

  int rA = t >> 3, cg = t & 7;
  int pr_off = cg >> 1;
  int px_off = (cg & 1) * 8;
  int csw = cg ^ (rA & 7);
  const float* baseA[2];
  short* lA[2];
#pragma unroll
  for (int p = 0; p < 2; p++) {
    int m = m0 + rA + p * 32;
    int b = m / NPAT, pp = m - b * NPAT;
    int py = pp / 14, px = pp - py * 14;
    baseA[p] = img + (size_t)b * 3 * 50176 + (size_t)(py * 16) * 224 + px * 16 + px_off;
    lA[p] = &Al[(rA + p * 32) * 64 + csw * 8];
  }
  int rs = t >> 3;
  int cs = (t & 7) ^ (rs & 7);
  const short* gB0 = W + (size_t)(n0 + rs) * KCONV + cs * 8;
  const short* gB1 = W + (size_t)(n0 + rs + 32) * KCONV + cs * 8;

  int offA[2][2], offB[2][2];
#pragma unroll
  for (int kk = 0; kk < 2; kk++)
#pragma unroll
    for (int i = 0; i < 2; i++) {
      int ra = wm + i * 16 + ml;
      offA[kk][i] = ra * 64 + (((kk * 4 + quad) ^ m7) * 8);
      int rb = wn + i * 16 + ml;
      offB[kk][i] = rb * 64 + (((kk * 4 + quad) ^ m7) * 8);
    }

  floatx4 z = {0.f, 0.f, 0.f, 0.f};
  floatx4 acc[2][2] = {{z, z}, {z, z}};

  for (int k0 = 0; k0 < KCONV; k0 += 64) {
    int ch = k0 >> 8;
    int rr0 = (k0 & 255) >> 4;
    __syncthreads();
    gl_lds16(gB0 + k0, Bl + t * 8);
    gl_lds16(gB1 + k0, Bl + t * 8 + 2048);
#pragma unroll
    for (int p = 0; p < 2; p++) {
      const float* ap = baseA[p] + (size_t)ch * 50176 + (rr0 + pr_off) * 224;
      float4 a0 = *(const float4*)ap;
      float4 a1 = *(const float4*)(ap + 4);
      short8 av;
      av[0] = f2b(a0.x); av[1] = f2b(a0.y); av[2] = f2b(a0.z); av[3] = f2b(a0.w);
      av[4] = f2b(a1.x); av[5] = f2b(a1.y); av[6] = f2b(a1.z); av[7] = f2b(a1.w);
      *(short8*)lA[p] = av;
    }
    __builtin_amdgcn_s_waitcnt(0x0F70);
    __syncthreads();
#pragma unroll
    for (int kk = 0; kk < 2; kk++) {
      short8 a0 = *(const short8*)&Al[offA[kk][0]];
      short8 a1 = *(const short8*)&Al[offA[kk][1]];
      short8 b0 = *(const short8*)&Bl[offB[kk][0]];
      short8 b1 = *(const short8*)&Bl[offB[kk][1]];
      acc[0][0] = __builtin_amdgcn_mfma_f32_16x16x32_bf16(a0, b0, acc[0][0], 0, 0, 0);
      acc[0][1] = __builtin_amdgcn_mfma_f32_16x16x32_bf16(a0, b1, acc[0][1], 0, 0, 0);
      acc[1][0] = __builtin_amdgcn_mfma_f32_16x16x32_bf16(a1, b0, acc[1][0], 0, 0, 0);
      acc[1][1] = __builtin_amdgcn_mfma_f32_16x16x32_bf16(a1, b1, acc[1][1], 0, 0, 0);
    }
  }
#pragma unroll
  for (int i = 0; i < 2; i++)
#pragma unroll
    for (int j = 0; j < 2; j++)
#pragma unroll
      for (int rr = 0; rr < 4; rr++) {
        int mrow = m0 + wm + i * 16 + quad * 4 + rr;
        int b2 = mrow / NPAT, p2 = mrow - b2 * NPAT;
        int col = n0 + wn + j * 16 + ml;
        e[((size_t)b2 * SEQ + p2) * DMODEL + col] =
            f2b(acc[i][j][rr] + cb[col] + pos[p2 * DMODEL + col]);
      }
}

// ---------------------------------------------------------------------------
// MFMA flash attention body, S^T formulation. bid2 in [0,1024):
// bh = bid2>>1 (b*8+h), half = bid2&1. 4 waves; each wave 2 query-tiles.
// smem usage: 37888 bytes.
// ---------------------------------------------------------------------------
__device__ __forceinline__ void attn_body(
    char* smem, int bid2,
    const short* __restrict__ qp, int qstr,
    const short* __restrict__ kp, int kstr,
    const short* __restrict__ vp, int vstr,
    const unsigned long long* __restrict__ mbits,
    short* __restrict__ op)
{
  short (*ks)[40] = (short(*)[40])smem;                     // SP*40 = 17920 B
  short (*vt)[SP + 8] = (short(*)[SP + 8])(smem + 17920);   // 32*232 = 14848 B
  short* psw = (short*)(smem + 32768);                      // 4*640 = 5120 B
  int bh = bid2 >> 1, half = bid2 & 1;
  int b = bh >> 3, h = bh & 7;
  int t = threadIdx.x;
  int wave = t >> 6, lane = t & 63;
  int ml = lane & 15, quad = lane >> 4;
  short* ps = psw + wave * 640;  // [16][40]

  const short* kb = kp + (size_t)b * SEQ * kstr + h * DKH;
  const short* vb = vp + (size_t)b * SEQ * vstr + h * DKH;
  for (int idx = t; idx < SEQ * 4; idx += 256) {
    int s = idx >> 2, c = (idx & 3) * 8;
    *(short8*)&ks[s][c] = *(const short8*)(kb + (size_t)s * kstr + c);
  }
  for (int idx = t; idx < SEQ * 4; idx += 256) {
    int s = idx >> 2, c = (idx & 3) * 8;
    short8 v8 = *(const short8*)(vb + (size_t)s * vstr + c);
#pragma unroll
    for (int j = 0; j < 8; j++) vt[c + j][s] = v8[j];
  }
  for (int idx = t; idx < DKH * (SP - SEQ); idx += 256) {
    int d = idx / (SP - SEQ), j = SEQ + idx - d * (SP - SEQ);
    vt[d][j] = 0;
  }
  __syncthreads();

  const float scale = 0.17677669529663687f;  // 1/sqrt(32)
  floatx4 z = {0.f, 0.f, 0.f, 0.f};

  for (int tt = 0; tt < 2; tt++) {
    int ti = half * 8 + wave * 2 + tt;  // 0..15; valid 0..12
    int q0 = ti * 16;
    if (q0 >= SEQ) continue;
    int qrow = q0 + ml;
    int qc = qrow < SEQ ? qrow : SEQ - 1;
    short8 qf = *(const short8*)(qp + ((size_t)b * SEQ + qc) * qstr + h * DKH + quad * 8);
    const unsigned long long* mrow = mbits + (size_t)qc * 4;

    floatx4 accO0 = z, accO1 = z;
    float mrun = -1e30f, lrun = 0.f;

    for (int st = 0; st < 7; st++) {
      int j0 = st * 32;
      short8 k0 = *(const short8*)&ks[j0 + ml][quad * 8];
      short8 k1 = *(const short8*)&ks[j0 + 16 + ml][quad * 8];
      floatx4 s0 = __builtin_amdgcn_mfma_f32_16x16x32_bf16(k0, qf, z, 0, 0, 0);
      floatx4 s1 = __builtin_amdgcn_mfma_f32_16x16x32_bf16(k1, qf, z, 0, 0, 0);
      unsigned long long mb = mrow[j0 >> 6] >> (j0 & 63);
      float sv[8];
#pragma unroll
      for (int r = 0; r < 4; r++) {
        int jl = quad * 4 + r;
        sv[r]     = ((mb >> jl) & 1ull)        ? s0[r] * scale : -1e38f;
        sv[4 + r] = ((mb >> (16 + jl)) & 1ull) ? s1[r] * scale : -1e38f;
      }
      float tm = sv[0];
#pragma unroll
      for (int i = 1; i < 8; i++) tm = fmaxf(tm, sv[i]);
      tm = fmaxf(tm, __shfl_xor(tm, 16));
      tm = fmaxf(tm, __shfl_xor(tm, 32));
      float nm = fmaxf(mrun, tm);
      float alpha = __expf(mrun - nm);
      float pv[8];
      float psum = 0.f;
#pragma unroll
      for (int i = 0; i < 8; i++) { pv[i] = __expf(sv[i] - nm); psum += pv[i]; }
      psum += __shfl_xor(psum, 16);
      psum += __shfl_xor(psum, 32);
      lrun = lrun * alpha + psum;
      mrun = nm;
      accO0 = accO0 * alpha;
      accO1 = accO1 * alpha;
      short4v p0, p1;
#pragma unroll
      for (int r = 0; r < 4; r++) { p0[r] = f2b(pv[r]); p1[r] = f2b(pv[4 + r]); }
      *(short4v*)&ps[ml * 40 + quad * 4]      = p0;
      *(short4v*)&ps[ml * 40 + 16 + quad * 4] = p1;
      __asm__ volatile("s_waitcnt lgkmcnt(0)" ::: "memory");  // wave-local RAW
      short8 pf = *(const short8*)&ps[ml * 40 + quad * 8];
      short8 vf0 = *(const short8*)&vt[ml][j0 + quad * 8];
      short8 vf1 = *(const short8*)&vt[16 + ml][j0 + quad * 8];
      accO0 = __builtin_amdgcn_mfma_f32_16x16x32_bf16(vf0, pf, accO0, 0, 0, 0);
      accO1 = __builtin_amdgcn_mfma_f32_16x16x32_bf16(vf1, pf, accO1, 0, 0, 0);
    }
    if (qrow < SEQ) {
      float inv = 1.f / lrun;
      short* ob = op + ((size_t)b * SEQ + qrow) * DMODEL + h * DKH;
      short4v o0, o1;
#pragma unroll
      for (int r = 0; r < 4; r++) {
        o0[r] = f2b(accO0[r] * inv);
        o1[r] = f2b(accO1[r] * inv);
      }
      *(short4v*)(ob + quad * 4)      = o0;
      *(short4v*)(ob + 16 + quad * 4) = o1;
    }
  }
}

// ---------------------------------------------------------------------------
// Phase 0: weight prep + mask pack + cls row + dec fp32->bf16 (fused)
// grid: 1024 prep | 4 mask | 64 cls | 1576 convert = 2668 blocks
// ---------------------------------------------------------------------------
__global__ __launch_bounds__(256) void phase0(
    const float* wq1, const float* wk1, const float* wv1,
    const float* bq1, const float* bk1, const float* bv1,
    const float* wq2, const float* wk2, const float* bq2, const float* bk2,
    const float* wv2s, const float* wo1, const float* wo2,
    const float* ffw1, const float* ffw2, const float* convw,
    short* Wqkv1, float* Bqkv1, short* Wqk2, float* Bqk2,
    short* Wv2, short* Wo1, short* Wo2, short* Wff1, short* Wff2, short* Wconv,
    const int* mask, unsigned long long* bits, unsigned long long* ones,
    const float* cls, const float* pos, short* e,
    const float* dec, short* dec_bf)
{
  int bid = blockIdx.x;
  int t = threadIdx.x;
  if (bid < 1024) {
    int i = bid * 256 + t;
    if (i < 65536) {
      Wqkv1[i] = f2b(wq1[i]); Wqkv1[65536 + i] = f2b(wk1[i]); Wqkv1[131072 + i] = f2b(wv1[i]);
      Wqk2[i] = f2b(wq2[i]);  Wqk2[65536 + i] = f2b(wk2[i]);
      Wv2[i] = f2b(wv2s[i]);  Wo1[i] = f2b(wo1[i]);  Wo2[i] = f2b(wo2[i]);
    }
    Wff1[i] = f2b(ffw1[i]); Wff2[i] = f2b(ffw2[i]);
    if (i < 196608) Wconv[i] = f2b(convw[i]);
    if (i < 256) {
      Bqkv1[i] = bq1[i]; Bqkv1[256 + i] = bk1[i]; Bqkv1[512 + i] = bv1[i];
      Bqk2[i] = bq2[i];  Bqk2[256 + i] = bk2[i];
    }
  } else if (bid < 1028) {
    int idx = (bid - 1024) * 256 + t;
    if (idx < SEQ * 4) {
      int r = idx >> 2, w = idx & 3;
      unsigned long long bb = 0ull, oo = 0ull;
      for (int j = 0; j < 64; j++) {
        int c = w * 64 + j;
        if (c < SEQ) {
          oo |= (1ull << j);
          if (mask[r * SEQ + c] != 0) bb |= (1ull << j);
        }
      }
      bits[idx] = bb;
      ones[idx] = oo;
    }
  } else if (bid < 1092) {
    int b = bid - 1028, d = t;
    e[((size_t)b * SEQ + NPAT) * DMODEL + d] = f2b(cls[d] + pos[NPAT * DMODEL + d]);
  } else {
    const int ND = (MROWS * DMODEL) / 8;
    int i = (bid - 1092) * 256 + t;
    if (i < ND) {
      float4 a0 = ((const float4*)dec)[i * 2];
      float4 a1 = ((const float4*)dec)[i * 2 + 1];
      short8 o;
      o[0] = f2b(a0.x); o[1] = f2b(a0.y); o[2] = f2b(a0.z); o[3] = f2b(a0.w);
      o[4] = f2b(a1.x); o[5] = f2b(a1.y); o[6] = f2b(a1.z); o[7] = f2b(a1.w);
      ((short8*)dec_bf)[i] = o;
    }
  }
}

// ---------------------------------------------------------------------------
// Phase 1: conv (784) | qkv1 gemm (2364) | v2 gemm (788) = 3936 blocks
// ---------------------------------------------------------------------------
__global__ __launch_bounds__(256) void phase1(
    const float* __restrict__ enc, const short* __restrict__ Wconv,
    const float* __restrict__ conv_b, const float* __restrict__ pos,
    short* __restrict__ e_bf,
    const short* __restrict__ dec_bf,
    const short* __restrict__ Wqkv1, const float* __restrict__ Bqkv1,
    short* __restrict__ qkv1,
    const short* __restrict__ Wv2, const float* __restrict__ bv2,
    short* __restrict__ v2)
{
  __shared__ char smem[32768];
  int bid = blockIdx.x;
  if (bid < 784) {
    conv64_body(smem, bid % 196, bid / 196, enc, Wconv, conv_b, pos, e_bf);
  } else if (bid < 3148) {
    int idx = bid - 784;
    gemm64_body(smem, idx % 197, idx / 197, dec_bf, Wqkv1, Bqkv1, nullptr,
                nullptr, qkv1, 768, 256, 0);
  } else {
    int idx = bid - 3148;
    gemm64_body(smem, idx % 197, idx / 197, dec_bf, Wv2, bv2, nullptr,
                nullptr, v2, 256, 256, 0);
  }
}

// ---------------------------------------------------------------------------
// Phase 2: attn1 (1024) | qk2 gemm (1576) = 2600 blocks
// ---------------------------------------------------------------------------
__global__ __launch_bounds__(256) void phase2(
    const short* __restrict__ qkv1, const unsigned long long* __restrict__ mones,
    short* __restrict__ o1,
    const short* __restrict__ e_bf, const short* __restrict__ Wqk2,
    const float* __restrict__ Bqk2, short* __restrict__ qk2)
{
  __shared__ char smem[37888];
  int bid = blockIdx.x;
  if (bid < 1024) {
    attn_body(smem, bid, qkv1, 768, qkv1 + 256, 768, qkv1 + 512, 768, mones, o1);
  } else {
    int idx = bid - 1024;
    gemm64_body(smem, idx % 197, idx / 197, e_bf, Wqk2, Bqk2, nullptr,
                nullptr, qk2, 512, 256, 0);
  }
}

// ---------------------------------------------------------------------------
// Phase 3: wo1 gemm (788) | attn2 (1024) = 1812 blocks
// ---------------------------------------------------------------------------
__global__ __launch_bounds__(256) void phase3(
    const short* __restrict__ o1, const short* __restrict__ Wo1,
    const float* __restrict__ bo1, const short* __restrict__ dec_bf,
    short* __restrict__ t_bf,
    const short* __restrict__ qk2, const short* __restrict__ v2,
    const unsigned long long* __restrict__ mbits, short* __restrict__ o2)
{
  __shared__ char smem[37888];
  int bid = blockIdx.x;
  if (bid < 788) {
    gemm64_body(smem, bid % 197, bid / 197, o1, Wo1, bo1, dec_bf,
                nullptr, t_bf, 256, 256, 0);
  } else {
    attn_body(smem, bid - 788, qk2, 512, qk2 + 256, 512, v2, 256, mbits, o2);
  }
}

// ---------------------------------------------------------------------------
// Standalone pipelined GEMM kernel (wo2 / ff1 / ff2)
// ---------------------------------------------------------------------------
__global__ __launch_bounds__(256) void gemm_k(
    const short* __restrict__ A, const short* __restrict__ W,
    const float* __restrict__ bias, const short* __restrict__ resb,
    float* __restrict__ outf, short* __restrict__ outb, int N, int K, int relu)
{
  __shared__ char smem[32768];
  gemm64_body(smem, blockIdx.x, blockIdx.y, A, W, bias, resb, outf, outb, N, K, relu);
}

// ---------------------------------------------------------------------------
// LayerNorm over D=256 from bf16 input, one wave per row (4 rows/block).
// ---------------------------------------------------------------------------
__global__ __launch_bounds__(256) void ln_bf(
    const short* __restrict__ x, const float* __restrict__ g,
    const float* __restrict__ bt, float* __restrict__ outf,
    short* __restrict__ outb)
{
  int wave = threadIdx.x >> 6, lane = threadIdx.x & 63;
  int row = blockIdx.x * 4 + wave;
  short4v xv = *(const short4v*)(x + (size_t)row * DMODEL + lane * 4);
  float v0 = b2f(xv[0]), v1 = b2f(xv[1]), v2 = b2f(xv[2]), v3 = b2f(xv[3]);
  float s = v0 + v1 + v2 + v3;
  for (int off = 32; off; off >>= 1) s += __shfl_down(s, off);
  s = __shfl(s, 0);
  float mean = s * (1.0f / DMODEL);
  float d0 = v0 - mean, d1 = v1 - mean, d2 = v2 - mean, d3 = v3 - mean;
  float vv = d0 * d0 + d1 * d1 + d2 * d2 + d3 * d3;
  for (int off = 32; off; off >>= 1) vv += __shfl_down(vv, off);
  vv = __shfl(vv, 0);
  float inv = rsqrtf(vv * (1.0f / DMODEL) + EPSLN);
  float4 gg = *(const float4*)(g + lane * 4);
  float4 bb = *(const float4*)(bt + lane * 4);
  float r0 = d0 * inv * gg.x + bb.x;
  float r1 = d1 * inv * gg.y + bb.y;
  float r2 = d2 * inv * gg.z + bb.z;
  float r3 = d3 * inv * gg.w + bb.w;
  if (outf) {
    float4 o = {r0, r1, r2, r3};
    *(float4*)(outf + (size_t)row * DMODEL + lane * 4) = o;
  }
  if (outb) {
    short4v o;
    o[0] = f2b(r0); o[1] = f2b(r1); o[2] = f2b(r2); o[3] = f2b(r3);
    *(short4v*)(outb + (size_t)row * DMODEL + lane * 4) = o;
  }
}

// ---------------------------------------------------------------------------
extern "C" void kernel_launch(void* const* d_in, const int* in_sizes, int n_in,
                              void* d_out, int out_size, void* d_ws, size_t ws_size,
                              hipStream_t stream)
{
  const float* enc    = (const float*)d_in[0];
  const float* dec_in = (const float*)d_in[1];
  const int*   mask   = (const int*)  d_in[2];
  const float* conv_w = (const float*)d_in[3];
  const float* conv_b = (const float*)d_in[4];
  const float* cls    = (const float*)d_in[5];
  const float* pos    = (const float*)d_in[6];
  const float* ff_w1  = (const float*)d_in[7];
  const float* ff_b1  = (const float*)d_in[8];
  const float* ff_w2  = (const float*)d_in[9];
  const float* ff_b2  = (const float*)d_in[10];
  const float* ln1_g  = (const float*)d_in[11];
  const float* ln1_b  = (const float*)d_in[12];
  const float* ln2_g  = (const float*)d_in[13];
  const float* ln2_b  = (const float*)d_in[14];
  const float* ln3_g  = (const float*)d_in[15];
  const float* ln3_b  = (const float*)d_in[16];
  const float* a1_wq = (const float*)d_in[17]; const float* a1_bq = (const float*)d_in[18];
  const float* a1_wk = (const float*)d_in[19]; const float* a1_bk = (const float*)d_in[20];
  const float* a1_wv = (const float*)d_in[21]; const float* a1_bv = (const float*)d_in[22];
  const float* a1_wo = (const float*)d_in[23]; const float* a1_bo = (const float*)d_in[24];
  const float* a2_wq = (const float*)d_in[25]; const float* a2_bq = (const float*)d_in[26];
  const float* a2_wk = (const float*)d_in[27]; const float* a2_bk = (const float*)d_in[28];
  const float* a2_wv = (const float*)d_in[29]; const float* a2_bv = (const float*)d_in[30];
  const float* a2_wo = (const float*)d_in[31]; const float* a2_bo = (const float*)d_in[32];

  // ---- workspace layout ----
  char* wsB = (char*)d_ws;
  short* Wqkv1 = (short*)wsB;
  short* Wqk2  = Wqkv1 + 196608;
  short* Wv2   = Wqk2 + 131072;
  short* Wo1   = Wv2 + 65536;
  short* Wo2   = Wo1 + 65536;
  short* Wff1  = Wo2 + 65536;
  short* Wff2  = Wff1 + 262144;
  short* Wconv = Wff2 + 262144;
  float* Bqkv1 = (float*)(Wconv + 196608);
  float* Bqk2  = Bqkv1 + 768;
  unsigned long long* mbits = (unsigned long long*)(Bqk2 + 512);
  unsigned long long* mones = mbits + 788;

  const size_t MB = 1048576;
  short* dec_bf = (short*)(wsB + 3 * MB);
  short* e_bf   = (short*)(wsB + 10 * MB);
  short* qkv1   = (short*)(wsB + 17 * MB);
  short* o1     = (short*)(wsB + 37 * MB);
  short* qk2    = (short*)(wsB + 44 * MB);
  short* v2     = (short*)(wsB + 57 * MB);
  short* h_buf  = (short*)(wsB + 64 * MB);
  short* t_bf   = (short*)(wsB + 90 * MB);
  short* x1b    = (short*)(wsB + 97 * MB);
  short* x2b    = (short*)(wsB + 104 * MB);
  short* o2     = o1;

  dim3 blk(256);
  const int M = MROWS;

  phase0<<<2668, blk, 0, stream>>>(
      a1_wq, a1_wk, a1_wv, a1_bq, a1_bk, a1_bv,
      a2_wq, a2_wk, a2_bq, a2_bk, a2_wv, a1_wo, a2_wo,
      ff_w1, ff_w2, conv_w,
      Wqkv1, Bqkv1, Wqk2, Bqk2, Wv2, Wo1, Wo2, Wff1, Wff2, Wconv,
      mask, mbits, mones, cls, pos, e_bf, dec_in, dec_bf);

  phase1<<<3936, blk, 0, stream>>>(
      enc, Wconv, conv_b, pos, e_bf,
      dec_bf, Wqkv1, Bqkv1, qkv1, Wv2, a2_bv, v2);

  phase2<<<2600, blk, 0, stream>>>(
      qkv1, mones, o1, e_bf, Wqk2, Bqk2, qk2);

  phase3<<<1812, blk, 0, stream>>>(
      o1, Wo1, a1_bo, dec_bf, t_bf, qk2, v2, mbits, o2);

  ln_bf<<<M / 4, blk, 0, stream>>>(t_bf, ln1_g, ln1_b, nullptr, x1b);

  gemm_k<<<dim3(197, 4), blk, 0, stream>>>(
      o2, Wo2, a2_bo, x1b, nullptr, t_bf, 256, 256, 0);

  ln_bf<<<M / 4, blk, 0, stream>>>(t_bf, ln2_g, ln2_b, nullptr, x2b);

  gemm_k<<<dim3(197, 16), blk, 0, stream>>>(
      x2b, Wff1, ff_b1, nullptr, nullptr, h_buf, FFDIM, 256, 1);

  gemm_k<<<dim3(197, 4), blk, 0, stream>>>(
      h_buf, Wff2, ff_b2, x2b, nullptr, t_bf, 256, 1024, 0);

  ln_bf<<<M / 4, blk, 0, stream>>>(t_bf, ln3_g, ln3_b, (float*)d_out, nullptr);
}